// Round 1
// baseline (169.638 us; speedup 1.0000x reference)
//
#include <hip/hip_runtime.h>

constexpr int N_ROWS = 8192;   // n == m == 8192
constexpr int DIM    = 64;
constexpr int TILE   = 128;    // output tile edge per block

// ---------------------------------------------------------------------------
// Kernel 1: per-row squared norms of X and Y into workspace.
// ---------------------------------------------------------------------------
__global__ void __launch_bounds__(256)
row_norms_kernel(const float* __restrict__ X, const float* __restrict__ Y,
                 float* __restrict__ x2, float* __restrict__ y2) {
    const int r = blockIdx.x * blockDim.x + threadIdx.x;   // exact grid, no guard
    const float4* xr = reinterpret_cast<const float4*>(X + (size_t)r * DIM);
    const float4* yr = reinterpret_cast<const float4*>(Y + (size_t)r * DIM);
    float sx = 0.f, sy = 0.f;
#pragma unroll
    for (int j = 0; j < DIM / 4; ++j) {
        float4 a = xr[j];
        sx = fmaf(a.x, a.x, fmaf(a.y, a.y, fmaf(a.z, a.z, fmaf(a.w, a.w, sx))));
        float4 b = yr[j];
        sy = fmaf(b.x, b.x, fmaf(b.y, b.y, fmaf(b.z, b.z, fmaf(b.w, b.w, sy))));
    }
    x2[r] = sx;
    y2[r] = sy;
}

// ---------------------------------------------------------------------------
// Kernel 2: 128x128 output tile per 256-thread block; 8x8 fp32 accumulators
// per thread. K = 64 (full depth, no K loop over tiles). LDS holds both tiles
// transposed [k][row] so the inner loop reads contiguous float4s.
// LDS: 2 * 64 * 128 * 4 B = 64 KiB exactly.
// ---------------------------------------------------------------------------
__global__ void __launch_bounds__(256)
rbf_tile_kernel(const float* __restrict__ X, const float* __restrict__ Y,
                const float* __restrict__ x2, const float* __restrict__ y2,
                float* __restrict__ out) {
    __shared__ float Xt[DIM][TILE];   // [k][row]
    __shared__ float Yt[DIM][TILE];   // [k][col]

    const int tid  = threadIdx.x;
    const int row0 = blockIdx.y * TILE;
    const int col0 = blockIdx.x * TILE;

    // ---- stage both tiles transposed into LDS ----
    // thread t handles row r = t/2, half h = t%2 (32 floats = 8 float4s).
    // LDS write bank = row % 32 -> 32 distinct rows per wave -> conflict-free.
    {
        const int r = tid >> 1;
        const int h = tid & 1;
        const float4* xr =
            reinterpret_cast<const float4*>(X + (size_t)(row0 + r) * DIM + h * 32);
        const float4* yr =
            reinterpret_cast<const float4*>(Y + (size_t)(col0 + r) * DIM + h * 32);
#pragma unroll
        for (int j = 0; j < 8; ++j) {
            float4 a = xr[j];
            float4 b = yr[j];
            const int k = h * 32 + j * 4;
            Xt[k + 0][r] = a.x; Xt[k + 1][r] = a.y;
            Xt[k + 2][r] = a.z; Xt[k + 3][r] = a.w;
            Yt[k + 0][r] = b.x; Yt[k + 1][r] = b.y;
            Yt[k + 2][r] = b.z; Yt[k + 3][r] = b.w;
        }
    }
    __syncthreads();

    // thread (tx, ty): rows {ty*4 + i, ty*4 + 64 + i}, cols {tx*4 + j, tx*4 + 64 + j}
    // b-read: 16 lanes at stride 4 floats -> 2 lanes/bank-group -> free (m136).
    // a-read: 4 distinct addresses per wave, 16-lane broadcast each -> free.
    const int tx = tid & 15;
    const int ty = tid >> 4;

    float acc[8][8];
#pragma unroll
    for (int i = 0; i < 8; ++i)
#pragma unroll
        for (int j = 0; j < 8; ++j) acc[i][j] = 0.f;

#pragma unroll 16
    for (int k = 0; k < DIM; ++k) {
        const float4 a0 = *reinterpret_cast<const float4*>(&Xt[k][ty * 4]);
        const float4 a1 = *reinterpret_cast<const float4*>(&Xt[k][ty * 4 + 64]);
        const float4 b0 = *reinterpret_cast<const float4*>(&Yt[k][tx * 4]);
        const float4 b1 = *reinterpret_cast<const float4*>(&Yt[k][tx * 4 + 64]);
        const float a[8] = {a0.x, a0.y, a0.z, a0.w, a1.x, a1.y, a1.z, a1.w};
        const float b[8] = {b0.x, b0.y, b0.z, b0.w, b1.x, b1.y, b1.z, b1.w};
#pragma unroll
        for (int i = 0; i < 8; ++i)
#pragma unroll
            for (int j = 0; j < 8; ++j)
                acc[i][j] = fmaf(a[i], b[j], acc[i][j]);
    }

    // ---- epilogue: dist2 = x2 + y2 - 2*xy, clamp, exp, store ----
    float xs[8], ys[8];
#pragma unroll
    for (int i = 0; i < 8; ++i)
        xs[i] = x2[row0 + ty * 4 + (i & 3) + (i >> 2) * 64];
#pragma unroll
    for (int j = 0; j < 8; ++j)
        ys[j] = y2[col0 + tx * 4 + (j & 3) + (j >> 2) * 64];

#pragma unroll
    for (int i = 0; i < 8; ++i) {
        const int ri = row0 + ty * 4 + (i & 3) + (i >> 2) * 64;
        float o[8];
#pragma unroll
        for (int j = 0; j < 8; ++j) {
            float d = fmaf(-2.f, acc[i][j], xs[i] + ys[j]);
            d = fmaxf(d, 0.f);
            o[j] = __expf(-d);            // GAMMA == 1.0
        }
        float* base = out + (size_t)ri * N_ROWS + col0 + tx * 4;
        *reinterpret_cast<float4*>(base)      = make_float4(o[0], o[1], o[2], o[3]);
        *reinterpret_cast<float4*>(base + 64) = make_float4(o[4], o[5], o[6], o[7]);
    }
}

// ---------------------------------------------------------------------------
extern "C" void kernel_launch(void* const* d_in, const int* in_sizes, int n_in,
                              void* d_out, int out_size, void* d_ws, size_t ws_size,
                              hipStream_t stream) {
    const float* X = (const float*)d_in[0];
    const float* Y = (const float*)d_in[1];
    float* out = (float*)d_out;
    float* x2  = (float*)d_ws;          // 8192 floats
    float* y2  = x2 + N_ROWS;           // 8192 floats

    row_norms_kernel<<<N_ROWS / 256, 256, 0, stream>>>(X, Y, x2, y2);

    dim3 grid(N_ROWS / TILE, N_ROWS / TILE);   // 64 x 64 blocks
    rbf_tile_kernel<<<grid, 256, 0, stream>>>(X, Y, x2, y2, out);
}

// Round 2
// 72.677 us; speedup vs baseline: 2.3341x; 2.3341x over previous
//
#include <hip/hip_runtime.h>

typedef __attribute__((ext_vector_type(8))) short  short8_t;   // 8 bf16 (4 VGPRs)
typedef __attribute__((ext_vector_type(8))) unsigned short ushort8_t;
typedef __attribute__((ext_vector_type(4))) float  floatx4;    // MFMA C/D

constexpr int N_ROWS = 8192;
constexpr int DIM    = 64;
constexpr int TILE   = 128;

// f32 -> bf16 round-to-nearest-even (no NaN handling needed for this data)
__device__ __forceinline__ unsigned short bf16_rne(float f) {
    unsigned int u = __float_as_uint(f);
    u += 0x7FFFu + ((u >> 16) & 1u);
    return (unsigned short)(u >> 16);
}

// ---------------------------------------------------------------------------
// Kernel 1: per-row squared norms of X and Y into workspace (fp32 exact-ish).
// ---------------------------------------------------------------------------
__global__ void __launch_bounds__(256)
row_norms_kernel(const float* __restrict__ X, const float* __restrict__ Y,
                 float* __restrict__ x2, float* __restrict__ y2) {
    const int r = blockIdx.x * blockDim.x + threadIdx.x;
    const float4* xr = reinterpret_cast<const float4*>(X + (size_t)r * DIM);
    const float4* yr = reinterpret_cast<const float4*>(Y + (size_t)r * DIM);
    float sx = 0.f, sy = 0.f;
#pragma unroll
    for (int j = 0; j < DIM / 4; ++j) {
        float4 a = xr[j];
        sx = fmaf(a.x, a.x, fmaf(a.y, a.y, fmaf(a.z, a.z, fmaf(a.w, a.w, sx))));
        float4 b = yr[j];
        sy = fmaf(b.x, b.x, fmaf(b.y, b.y, fmaf(b.z, b.z, fmaf(b.w, b.w, sy))));
    }
    x2[r] = sx;
    y2[r] = sy;
}

// ---------------------------------------------------------------------------
// Kernel 2: split-bf16 MFMA. xy = Xh.Yh + Xh.Yl + Xl.Yh (lo*lo dropped).
// 128x128 tile / 256 threads; wave w owns 64x64 quadrant (4x4 16x16 frags).
// LDS: Xh,Xl,Yh,Yl each [128][64] bf16 = 16 KiB -> 64 KiB total, 2 blocks/CU.
// XOR swizzle (idx ^= (row&7)*8, ushort units == byte ^ (row&7)<<4) breaks the
// 128-B-row-stride 32-way bank conflict down to free 2-way (G4 / m136).
// ---------------------------------------------------------------------------
__global__ void __launch_bounds__(256, 2)
rbf_mfma_kernel(const float* __restrict__ X, const float* __restrict__ Y,
                const float* __restrict__ x2, const float* __restrict__ y2,
                float* __restrict__ out) {
    __shared__ unsigned short smem[4 * TILE * DIM];   // 64 KiB
    constexpr int XH = 0 * TILE * DIM;
    constexpr int XL = 1 * TILE * DIM;
    constexpr int YH = 2 * TILE * DIM;
    constexpr int YL = 3 * TILE * DIM;

    const int tid  = threadIdx.x;
    const int row0 = blockIdx.y * TILE;
    const int col0 = blockIdx.x * TILE;

    // ---- stage + convert: thread t -> row r = t>>1, k-half h = t&1 ----
    {
        const int r = tid >> 1;
        const int h = tid & 1;
        const float* xr = X + (size_t)(row0 + r) * DIM + h * 32;
        const float* yr = Y + (size_t)(col0 + r) * DIM + h * 32;
        const int swz = (r & 7) * 8;           // ushort-unit XOR (bits 3..5)
#pragma unroll
        for (int jj = 0; jj < 4; ++jj) {
            const int k0  = h * 32 + jj * 8;
            const int idx = ((r * DIM + k0) ^ swz);
            float f[8];
            *reinterpret_cast<float4*>(&f[0]) = *reinterpret_cast<const float4*>(xr + jj * 8);
            *reinterpret_cast<float4*>(&f[4]) = *reinterpret_cast<const float4*>(xr + jj * 8 + 4);
            ushort8_t hi, lo;
#pragma unroll
            for (int e = 0; e < 8; ++e) {
                unsigned short hh = bf16_rne(f[e]);
                hi[e] = hh;
                lo[e] = bf16_rne(f[e] - __uint_as_float((unsigned int)hh << 16));
            }
            *reinterpret_cast<ushort8_t*>(&smem[XH + idx]) = hi;
            *reinterpret_cast<ushort8_t*>(&smem[XL + idx]) = lo;

            *reinterpret_cast<float4*>(&f[0]) = *reinterpret_cast<const float4*>(yr + jj * 8);
            *reinterpret_cast<float4*>(&f[4]) = *reinterpret_cast<const float4*>(yr + jj * 8 + 4);
#pragma unroll
            for (int e = 0; e < 8; ++e) {
                unsigned short hh = bf16_rne(f[e]);
                hi[e] = hh;
                lo[e] = bf16_rne(f[e] - __uint_as_float((unsigned int)hh << 16));
            }
            *reinterpret_cast<ushort8_t*>(&smem[YH + idx]) = hi;
            *reinterpret_cast<ushort8_t*>(&smem[YL + idx]) = lo;
        }
    }
    __syncthreads();

    const int lane = tid & 63;
    const int w    = tid >> 6;
    const int wr   = (w >> 1) * 64;    // wave row offset in tile
    const int wc   = (w & 1) * 64;     // wave col offset in tile
    const int li   = lane & 15;
    const int lg   = lane >> 4;

    floatx4 acc[4][4] = {};            // 64 VGPRs of f32 accumulator

    // frag loader: row-major [row][k] bf16 tile, A-row / B-col = base+li,
    // k = ks*32 + lg*8 .. +8 (v_mfma_f32_16x16x32_bf16 operand layout)
    const int kfrag = lg * 8;
#define FRAG(base, rowbase, ks)                                                \
    (*reinterpret_cast<const short8_t*>(                                       \
        &smem[(base) + ((((rowbase) + li) * DIM + (ks) * 32 + kfrag)           \
                        ^ ((((rowbase) + li) & 7) * 8))]))

    // 6 k-steps: (Xh,Yh)ks0/1, (Xh,Yl)ks0/1, (Xl,Yh)ks0/1
    const int stepA[6] = {XH, XH, XH, XH, XL, XL};
    const int stepB[6] = {YH, YH, YL, YL, YH, YH};
    const int stepK[6] = {0, 1, 0, 1, 0, 1};
#pragma unroll
    for (int s = 0; s < 6; ++s) {
        short8_t a[4], b[4];
#pragma unroll
        for (int mi = 0; mi < 4; ++mi) a[mi] = FRAG(stepA[s], wr + mi * 16, stepK[s]);
#pragma unroll
        for (int ni = 0; ni < 4; ++ni) b[ni] = FRAG(stepB[s], wc + ni * 16, stepK[s]);
#pragma unroll
        for (int mi = 0; mi < 4; ++mi)
#pragma unroll
            for (int ni = 0; ni < 4; ++ni)
                acc[mi][ni] = __builtin_amdgcn_mfma_f32_16x16x32_bf16(
                    a[mi], b[ni], acc[mi][ni], 0, 0, 0);
    }
#undef FRAG

    // ---- epilogue: dist2 = x2 + y2 - 2*xy, clamp, exp, store ----
    float ys[4];
#pragma unroll
    for (int ni = 0; ni < 4; ++ni) ys[ni] = y2[col0 + wc + ni * 16 + li];

#pragma unroll
    for (int mi = 0; mi < 4; ++mi) {
        const int rbase = row0 + wr + mi * 16 + lg * 4;
#pragma unroll
        for (int j = 0; j < 4; ++j) {
            const float xs = x2[rbase + j];
            float* orow = out + (size_t)(rbase + j) * N_ROWS + col0 + wc + li;
#pragma unroll
            for (int ni = 0; ni < 4; ++ni) {
                float d = fmaf(-2.f, acc[mi][ni][j], xs + ys[ni]);
                d = fmaxf(d, 0.f);
                orow[ni * 16] = __expf(-d);     // GAMMA == 1.0
            }
        }
    }
}

// ---------------------------------------------------------------------------
extern "C" void kernel_launch(void* const* d_in, const int* in_sizes, int n_in,
                              void* d_out, int out_size, void* d_ws, size_t ws_size,
                              hipStream_t stream) {
    const float* X = (const float*)d_in[0];
    const float* Y = (const float*)d_in[1];
    float* out = (float*)d_out;
    float* x2  = (float*)d_ws;          // 8192 floats
    float* y2  = x2 + N_ROWS;           // 8192 floats

    row_norms_kernel<<<N_ROWS / 256, 256, 0, stream>>>(X, Y, x2, y2);

    dim3 grid(N_ROWS / TILE, N_ROWS / TILE);   // 64 x 64 blocks
    rbf_mfma_kernel<<<grid, 256, 0, stream>>>(X, Y, x2, y2, out);
}